// Round 5
// baseline (142.664 us; speedup 1.0000x reference)
//
#include <hip/hip_runtime.h>
#include <stdint.h>

#define NR 8192
#define DIM 512
#define BM 256
#define BN 256
#define BK 64
#define NT (DIM / BK)   // 8 K-tiles

typedef unsigned short u16;
typedef __attribute__((ext_vector_type(8))) __bf16 bf16x8;
typedef __attribute__((ext_vector_type(4))) float f32x4;

static __device__ __forceinline__ u16 f2bf(float f) {
    union { float f; uint32_t u; } v; v.f = f;
    uint32_t u = v.u;
    u += 0x7FFFu + ((u >> 16) & 1u);   // RNE
    return (u16)(u >> 16);
}

static __device__ __forceinline__ void gload_lds16(const void* g, void* l) {
    __builtin_amdgcn_global_load_lds(
        (__attribute__((address_space(1))) void*)(void*)g,
        (__attribute__((address_space(3))) void*)l,
        16, 0, 0);
}

// 32-bit LDS byte address for ds_* inline asm (AS3 pointers are 32-bit).
static __device__ __forceinline__ uint32_t lds_addr(const void* p) {
    return (uint32_t)(uintptr_t)(__attribute__((address_space(3))) const void*)p;
}

// One block per row: reciprocal norms, exact fp32 diag term, fp32->bf16
// conversion, and zero rowsum for this call.
__global__ void prep_kernel(const float* __restrict__ xi, const float* __restrict__ xj,
                            u16* __restrict__ xib, u16* __restrict__ xjb,
                            float* __restrict__ inv_ni, float* __restrict__ inv_nj,
                            float* __restrict__ diag, float* __restrict__ rowsum) {
    const int row = blockIdx.x;
    const int t = threadIdx.x;                 // 128 threads, 4 elems each
    const float4 a = ((const float4*)(xi + (size_t)row * DIM))[t];
    const float4 b = ((const float4*)(xj + (size_t)row * DIM))[t];

    float ssi = a.x*a.x + a.y*a.y + a.z*a.z + a.w*a.w;
    float ssj = b.x*b.x + b.y*b.y + b.z*b.z + b.w*b.w;
    float dot = a.x*b.x + a.y*b.y + a.z*b.z + a.w*b.w;

    ushort4 av = { f2bf(a.x), f2bf(a.y), f2bf(a.z), f2bf(a.w) };
    ushort4 bv = { f2bf(b.x), f2bf(b.y), f2bf(b.z), f2bf(b.w) };
    ((ushort4*)(xib + (size_t)row * DIM))[t] = av;
    ((ushort4*)(xjb + (size_t)row * DIM))[t] = bv;

    #pragma unroll
    for (int m = 32; m >= 1; m >>= 1) {
        ssi += __shfl_xor(ssi, m, 64);
        ssj += __shfl_xor(ssj, m, 64);
        dot += __shfl_xor(dot, m, 64);
    }
    __shared__ float red[6];
    const int wave = t >> 6, lane = t & 63;
    if (lane == 0) { red[wave*3+0] = ssi; red[wave*3+1] = ssj; red[wave*3+2] = dot; }
    __syncthreads();
    if (t == 0) {
        float si = red[0] + red[3];
        float sj = red[1] + red[4];
        float d  = red[2] + red[5];
        float ini = rsqrtf(fmaxf(si, 1e-30f));
        float inj = rsqrtf(fmaxf(sj, 1e-30f));
        inv_ni[row] = ini;
        inv_nj[row] = inj;
        diag[row] = d * ini * inj;
        rowsum[row] = 0.0f;
    }
}

// Fused NT-GEMM + exp + row-sum.
// 256x256 tile, BK=64, 8 waves (2Mx4N), 4 balanced phases per K-tile,
// double-buffered K-half units, counted vmcnt(4), conflict-free XOR swizzle.
// Fragment reads are inline-asm ds_read_b128 so the compiler's aliasing
// model cannot see them vs the in-flight global_load_lds writes -> no
// compiler-inserted vmcnt(0) drains; our explicit ledger is the only sync.
__global__ __launch_bounds__(512, 2)
void gemm_rowsum(const u16* __restrict__ A, const u16* __restrict__ B,
                 const float* __restrict__ inv_ni, const float* __restrict__ inv_nj,
                 float* __restrict__ rowsum) {
    __shared__ u16 lds[8][8192];   // 8 units x 16 KB = 128 KB
    char* const ldsA = (char*)&lds[0][0];   // A units (kk*2+parity): 0..64K
    char* const ldsB = ldsA + 65536;        // B units: 64K..128K

    const int tid = threadIdx.x;
    // XCD-aware, L2-aware: 32 concurrent blocks/XCD = 4 row-panels x 8
    // col-panels -> A 1MB + B 2MB = 3MB < 4MB per-XCD L2.
    const int orig = blockIdx.x;
    const int xcd = orig & 7, k = orig >> 3;
    const int by = xcd * 4 + (k & 3);
    const int bx = k >> 2;
    const int row0 = by * BM, col0 = bx * BN;

    // ---- staging (linear LDS dest; inverse-swizzled global src) ----
    // Unit rows = 64B (4 x 16B chunks). phys_chunk = logical ^ ((row>>1)&3).
    const int st_row = tid >> 2;                          // 0..127
    const int st_c   = (tid & 3) ^ ((st_row >> 1) & 3);   // global k-chunk
    const u16* gA = A + (size_t)(row0 + st_row) * DIM + st_c * 8;
    const u16* gB = B + (size_t)(col0 + st_row) * DIM + st_c * 8;
    const int stoff = tid * 16;

    // ---- fragment read bases (swizzled; 2-way max -> conflict-free) ----
    const int lane = tid & 63;
    const int lr = lane & 15, lk = lane >> 4;
    const int xsw = lk ^ ((lr >> 1) & 3);
    const int wid = tid >> 6;
    const int wm = wid >> 2, wn = wid & 3;                // 2M x 4N waves
    const uint32_t aBase0 = lds_addr(ldsA + wm * 8192 + lr * 64 + xsw * 16);
    const uint32_t aBase1 = aBase0 + 16384;
    const uint32_t bBase0 = lds_addr(ldsB + wn * 4096 + lr * 64 + xsw * 16);
    const uint32_t bBase1 = bBase0 + 16384;

    f32x4 acc[8][4] = {};
    bf16x8 af[4], bg[4];

#define DSR128(DST, BASE, IMM)                                                 \
    asm volatile("ds_read_b128 %0, %1 offset:%c2"                              \
                 : "=v"(DST) : "v"(BASE), "n"(IMM))

#define STAGE_A(KK, PN, TN) do {                                               \
    char* dst = ldsA + ((KK)*2 + (PN)) * 16384 + stoff;                        \
    const u16* g = gA + (TN) * BK + (KK) * 32;                                 \
    gload_lds16(g, dst);                                                       \
    gload_lds16(g + 128 * DIM, dst + 8192);                                    \
} while (0)

#define STAGE_B(KK, PN, TN) do {                                               \
    char* dst = ldsB + ((KK)*2 + (PN)) * 16384 + stoff;                        \
    const u16* g = gB + (TN) * BK + (KK) * 32;                                 \
    gload_lds16(g, dst);                                                       \
    gload_lds16(g + 128 * DIM, dst + 8192);                                    \
} while (0)

#define READ_AF(KK, PI, MH) do {                                               \
    const uint32_t b_ = (PI) ? aBase1 : aBase0;                                \
    DSR128(af[0], b_, (KK)*32768 + (MH)*4096 + 0);                             \
    DSR128(af[1], b_, (KK)*32768 + (MH)*4096 + 1024);                          \
    DSR128(af[2], b_, (KK)*32768 + (MH)*4096 + 2048);                          \
    DSR128(af[3], b_, (KK)*32768 + (MH)*4096 + 3072);                          \
} while (0)

#define READ_BG(KK, PI) do {                                                   \
    const uint32_t b_ = (PI) ? bBase1 : bBase0;                                \
    DSR128(bg[0], b_, (KK)*32768 + 0);                                         \
    DSR128(bg[1], b_, (KK)*32768 + 1024);                                      \
    DSR128(bg[2], b_, (KK)*32768 + 2048);                                      \
    DSR128(bg[3], b_, (KK)*32768 + 3072);                                      \
} while (0)

#define MFMA16(MH) do {                                                        \
    __builtin_amdgcn_s_setprio(1);                                             \
    _Pragma("unroll") for (int m = 0; m < 4; ++m)                              \
        _Pragma("unroll") for (int n = 0; n < 4; ++n)                          \
            acc[(MH)*4 + m][n] = __builtin_amdgcn_mfma_f32_16x16x32_bf16(      \
                af[m], bg[n], acc[(MH)*4 + m][n], 0, 0, 0);                    \
    __builtin_amdgcn_s_setprio(0);                                             \
} while (0)

#define LGKM0()  asm volatile("s_waitcnt lgkmcnt(0)" ::: "memory")
#define VMCNT(N) asm volatile("s_waitcnt vmcnt(" #N ")" ::: "memory")
#define BAR()    __builtin_amdgcn_s_barrier()
#define SCHED0() __builtin_amdgcn_sched_barrier(0)

    // ---- prologue: stage tile 0's four units; wait A0/B0 ----
    STAGE_A(0, 0, 0);
    STAGE_B(0, 0, 0);
    STAGE_A(1, 0, 0);
    STAGE_B(1, 0, 0);
    VMCNT(4);
    BAR();

    #pragma unroll
    for (int t = 0; t < NT; ++t) {
        const int pi = t & 1, pn = pi ^ 1;
        const bool st = (t < NT - 1);
        // ph0: kk=0, m-half 0
        READ_AF(0, pi, 0);
        READ_BG(0, pi);
        if (st) STAGE_A(0, pn, t + 1);
        BAR(); LGKM0(); SCHED0();
        MFMA16(0);
        BAR();
        // ph1: kk=0, m-half 1
        READ_AF(0, pi, 1);
        if (st) STAGE_B(0, pn, t + 1);
        BAR(); LGKM0(); SCHED0();
        MFMA16(1);
        if (st) VMCNT(4); else VMCNT(0);   // A1/B1 of this tile landed
        BAR();
        // ph2: kk=1, m-half 0
        READ_AF(1, pi, 0);
        READ_BG(1, pi);
        if (st) STAGE_A(1, pn, t + 1);
        BAR(); LGKM0(); SCHED0();
        MFMA16(0);
        BAR();
        // ph3: kk=1, m-half 1
        READ_AF(1, pi, 1);
        if (st) STAGE_B(1, pn, t + 1);
        BAR(); LGKM0(); SCHED0();
        MFMA16(1);
        if (st) VMCNT(4);                  // A0'/B0' of next tile landed
        BAR();
    }
#undef DSR128
#undef STAGE_A
#undef STAGE_B
#undef READ_AF
#undef READ_BG
#undef MFMA16
#undef LGKM0
#undef VMCNT
#undef BAR
#undef SCHED0

    // ---- epilogue: cosine scale, exp, row-reduce, one atomic per row ----
    float inj[4];
    #pragma unroll
    for (int n = 0; n < 4; ++n)
        inj[n] = inv_nj[col0 + wn * 64 + n * 16 + lr];

    #pragma unroll
    for (int m = 0; m < 8; ++m) {
        #pragma unroll
        for (int e = 0; e < 4; ++e) {
            const int row = row0 + wm * 128 + m * 16 + lk * 4 + e;
            const float in_i = inv_ni[row];
            float s = 0.0f;
            #pragma unroll
            for (int n = 0; n < 4; ++n)
                s += __expf(acc[m][n][e] * in_i * inj[n]);
            s += __shfl_xor(s, 1, 64);
            s += __shfl_xor(s, 2, 64);
            s += __shfl_xor(s, 4, 64);
            s += __shfl_xor(s, 8, 64);
            if (lr == 0)
                atomicAdd(&rowsum[row], s);
        }
    }
}

__global__ void finalize(const float* __restrict__ rowsum,
                         const float* __restrict__ diag,
                         float* __restrict__ out) {
    const float E1 = 2.7182818284590452f;  // exp(1/TAU)
    float acc = 0.0f;
    for (int i = threadIdx.x; i < NR; i += 256)
        acc += __logf(rowsum[i] - E1) - diag[i];
    #pragma unroll
    for (int m = 32; m >= 1; m >>= 1)
        acc += __shfl_xor(acc, m, 64);
    __shared__ float red[4];
    const int wave = threadIdx.x >> 6, lane = threadIdx.x & 63;
    if (lane == 0) red[wave] = acc;
    __syncthreads();
    if (threadIdx.x == 0)
        out[0] = (red[0] + red[1] + red[2] + red[3]) * (1.0f / NR);
}

extern "C" void kernel_launch(void* const* d_in, const int* in_sizes, int n_in,
                              void* d_out, int out_size, void* d_ws, size_t ws_size,
                              hipStream_t stream) {
    const float* xi = (const float*)d_in[0];
    const float* xj = (const float*)d_in[1];

    char* ws = (char*)d_ws;
    u16* xib = (u16*)ws;                                // 8 MB
    u16* xjb = xib + (size_t)NR * DIM;                  // 8 MB
    float* inv_ni = (float*)(xjb + (size_t)NR * DIM);   // 32 KB
    float* inv_nj = inv_ni + NR;
    float* diag   = inv_nj + NR;
    float* rowsum = diag + NR;

    prep_kernel<<<NR, 128, 0, stream>>>(xi, xj, xib, xjb, inv_ni, inv_nj, diag, rowsum);
    gemm_rowsum<<<(NR / BM) * (NR / BN), 512, 0, stream>>>(xib, xjb, inv_ni, inv_nj, rowsum);
    finalize<<<1, 256, 0, stream>>>(rowsum, diag, (float*)d_out);
}